// Round 5
// baseline (12072.506 us; speedup 1.0000x reference)
//
#include <hip/hip_runtime.h>

// ---------------------------------------------------------------------------
// EGNN scoring model, MI355X (gfx950).
// R5: FULL BRUTE-FORCE BISECTION ROUND. All clever components replaced by
// literal f32 implementations: serial-argmin KNN (exact top_k tie-break),
// direct dot-product linear layers (no MFMA, no fragments, no wave merges).
// Output confirmed f32 (R4's bf16 write made error worse). If this passes,
// the bug was in MFMA-GEMM / wave-KNN; reintroduce them one per round.
// ---------------------------------------------------------------------------

typedef unsigned int u32;
typedef unsigned long long u64;

#define NB 16
#define NN 2048
#define DD 142
#define KNNK 10
#define NNODES (NB * NN)        // 32768
#define NEDGES (NNODES * KNNK)  // 327680
#define E1OUT 610
#define APITCH 640

__device__ __forceinline__ float siluf(float x) { return x / (1.0f + __expf(-x)); }

// ---------------------------------------------------------------------------
// Brute KNN: one block per node. 256 threads fill d2s[2048] (bit-exact fp32,
// (dx2+dy2)+dz2 like np); thread 0 does 10 serial argmin passes with strict
// '<' (lowest index wins ties — matches stable top_k on -dist).
// ---------------------------------------------------------------------------
__global__ __launch_bounds__(256) void brute_knn(const float* __restrict__ coors,
                                                 int* __restrict__ idxo,
                                                 float* __restrict__ disto) {
  __shared__ float d2s[NN];
  int gi = blockIdx.x;  // global node 0..32767
  int b = gi >> 11, i = gi & 2047;
  const float* cb = coors + (size_t)b * NN * 3;
  float xi = cb[i * 3 + 0], yi = cb[i * 3 + 1], zi = cb[i * 3 + 2];
  for (int j = threadIdx.x; j < NN; j += 256) {
    float dx = __fadd_rn(xi, -cb[j * 3 + 0]);
    float dy = __fadd_rn(yi, -cb[j * 3 + 1]);
    float dz = __fadd_rn(zi, -cb[j * 3 + 2]);
    d2s[j] = __fadd_rn(__fadd_rn(__fmul_rn(dx, dx), __fmul_rn(dy, dy)), __fmul_rn(dz, dz));
  }
  __syncthreads();
  if (threadIdx.x == 0) {
    for (int t = 0; t < KNNK; ++t) {
      float best = d2s[0];
      int bj = 0;
      for (int j = 1; j < NN; ++j) {
        float v = d2s[j];
        if (v < best) { best = v; bj = j; }
      }
      idxo[(size_t)gi * KNNK + t] = b * NN + bj;  // GLOBAL index
      disto[(size_t)gi * KNNK + t] = best;
      d2s[bj] = 3.0e38f;  // exclude from later passes
    }
  }
}

// ---------------------------------------------------------------------------
// Brute linear: Y[n][e] = act(sum_k X[n][k]*W[r0+k][e] + bias[e]) + resid.
// 8 nodes per block, thread = output column (3 column slots of 256).
// Plain f32, ascending-k accumulation. No MFMA, no LDS tricks beyond X rows.
// ---------------------------------------------------------------------------
__global__ __launch_bounds__(256) void brute_lin(
    const float* __restrict__ X, int ldx, int K,
    const float* __restrict__ W, int ldw, int r0, int Ncols,
    const float* __restrict__ bias, const float* __restrict__ resid, int ldr,
    float* __restrict__ Y, int ldy, int doSilu) {
  __shared__ float Xs[8 * 284];
  int n0 = blockIdx.x * 8;
  int tid = threadIdx.x;
  for (int p = tid; p < 8 * K; p += 256) {
    int n = p / K, k = p - n * K;
    Xs[n * K + k] = X[(size_t)(n0 + n) * ldx + k];
  }
  __syncthreads();
  float acc[8][3];
#pragma unroll
  for (int n = 0; n < 8; ++n)
#pragma unroll
    for (int s = 0; s < 3; ++s) acc[n][s] = 0.0f;
  int e1 = tid + 256, e2 = tid + 512;
  for (int k = 0; k < K; ++k) {
    const float* wr = W + (size_t)(r0 + k) * ldw;
    float w0 = wr[tid];  // Ncols >= 142 > 255? no: guard below handles, but
                         // tid<256 may exceed Ncols for W_n2 (142): guard all.
    w0 = (tid < Ncols) ? w0 : 0.0f;
    float w1 = (e1 < Ncols) ? wr[e1] : 0.0f;
    float w2 = (e2 < Ncols) ? wr[e2] : 0.0f;
#pragma unroll
    for (int n = 0; n < 8; ++n) {
      float xv = Xs[n * K + k];
      acc[n][0] += xv * w0;
      acc[n][1] += xv * w1;
      acc[n][2] += xv * w2;
    }
  }
#pragma unroll
  for (int n = 0; n < 8; ++n) {
#pragma unroll
    for (int s = 0; s < 3; ++s) {
      int e = tid + s * 256;
      if (e < Ncols) {
        float v = acc[n][s];
        if (bias) v += bias[e];
        if (doSilu) v = siluf(v);
        if (resid) v += resid[(size_t)(n0 + n) * ldr + e];
        Y[(size_t)(n0 + n) * ldy + e] = v;
      }
    }
  }
}

// ---------------------------------------------------------------------------
// Edge kernel, plain fp32 (unchanged from R3). One wave per edge.
// ---------------------------------------------------------------------------
struct EdgeF32Lds {
  float WdT[640][22];
  float BE2[16];
  float DF[8][24];
};

__global__ __launch_bounds__(512) void edge_f32_kernel(
    const float* __restrict__ Ap, const float* __restrict__ Bmm,
    const int* __restrict__ idxE, const float* __restrict__ distE,
    const float* __restrict__ W_e1, const float* __restrict__ W_e2,
    const float* __restrict__ b_e2, float* __restrict__ m_i) {
  __shared__ EdgeF32Lds L;
  int tid = threadIdx.x;
  for (int p = tid; p < 21 * 640; p += 512) {
    int t = p / 640, e = p - t * 640;
    L.WdT[e][t] = (e < E1OUT) ? W_e1[(284 + t) * E1OUT + e] : 0.0f;
  }
  if (tid < 16) L.BE2[tid] = b_e2[tid];

  int wave = tid >> 6, lane = tid & 63;
  int E = blockIdx.x * 8 + wave;
  int i = E / 10;
  int j = idxE[E];
  float d2 = distE[E];
  if (lane < 21) {
    float v;
    if (lane < 10) v = sinf(d2 / (float)(1 << lane));
    else if (lane < 20) v = cosf(d2 / (float)(1 << (lane - 10)));
    else v = d2;
    L.DF[wave][lane] = v;
  }
  __syncthreads();

  float df[21];
#pragma unroll
  for (int t = 0; t < 21; ++t) df[t] = L.DF[wave][t];

  const float* aprow = Ap + (size_t)i * APITCH;
  const float* bmrow = Bmm + (size_t)j * APITCH;
  float z[16];
#pragma unroll
  for (int c = 0; c < 16; ++c) z[c] = 0.0f;

  for (int e = lane; e < E1OUT; e += 64) {
    float h = aprow[e] + bmrow[e];
#pragma unroll
    for (int t = 0; t < 21; ++t) h += df[t] * L.WdT[e][t];
    float hs = siluf(h);
    const float4* w2r = (const float4*)(W_e2 + e * 16);
    float4 w0 = w2r[0], w1 = w2r[1], w2 = w2r[2], w3 = w2r[3];
    z[0] += hs * w0.x;  z[1] += hs * w0.y;  z[2] += hs * w0.z;  z[3] += hs * w0.w;
    z[4] += hs * w1.x;  z[5] += hs * w1.y;  z[6] += hs * w1.z;  z[7] += hs * w1.w;
    z[8] += hs * w2.x;  z[9] += hs * w2.y;  z[10] += hs * w2.z; z[11] += hs * w2.w;
    z[12] += hs * w3.x; z[13] += hs * w3.y; z[14] += hs * w3.z; z[15] += hs * w3.w;
  }

  float zsel = 0.0f;
#pragma unroll
  for (int c = 0; c < 16; ++c) {
    float v = z[c];
#pragma unroll
    for (int off = 32; off >= 1; off >>= 1) v += __shfl_xor(v, off, 64);
    if (lane == c) zsel = v;
  }
  if (lane < 16) {
    float m = siluf(zsel + L.BE2[lane]);
    atomicAdd(&m_i[(size_t)i * 16 + lane], m);
  }
}

// ---------------------------------------------------------------------------
// LayerNorm + concat m_i -> node_in[32768][160]
// ---------------------------------------------------------------------------
__global__ __launch_bounds__(256) void node_prep(const float* __restrict__ feats,
                                                 const float* __restrict__ m_i,
                                                 const float* __restrict__ ln_g,
                                                 const float* __restrict__ ln_b,
                                                 float* __restrict__ node_in) {
  int wave = threadIdx.x >> 6, lane = threadIdx.x & 63;
  int i = blockIdx.x * 4 + wave;
  const float* fr = feats + (size_t)i * DD;
  float x0 = fr[lane];
  float x1 = fr[lane + 64];
  float x2 = (lane < 14) ? fr[lane + 128] : 0.0f;
  float s = x0 + x1 + x2;
#pragma unroll
  for (int off = 32; off >= 1; off >>= 1) s += __shfl_xor(s, off, 64);
  float mu = s / 142.0f;
  float d0 = x0 - mu, d1 = x1 - mu, d2 = (lane < 14) ? (x2 - mu) : 0.0f;
  float ss = d0 * d0 + d1 * d1 + d2 * d2;
#pragma unroll
  for (int off = 32; off >= 1; off >>= 1) ss += __shfl_xor(ss, off, 64);
  float var = ss / 142.0f;
  float rstd = 1.0f / sqrtf(var + 1e-5f);
  float* o = node_in + (size_t)i * 160;
  o[lane] = d0 * rstd * ln_g[lane] + ln_b[lane];
  o[lane + 64] = d1 * rstd * ln_g[lane + 64] + ln_b[lane + 64];
  if (lane < 14) o[lane + 128] = d2 * rstd * ln_g[lane + 128] + ln_b[lane + 128];
  if (lane < 16) o[142 + lane] = m_i[i * 16 + lane];
}

// ---------------------------------------------------------------------------
// Masked mean pool fused with head -> f32 emb accumulator in workspace.
// ---------------------------------------------------------------------------
__global__ __launch_bounds__(256) void pool_kernel(const float* __restrict__ node_out,
                                                   const float* __restrict__ W_out,
                                                   const float* __restrict__ b_out,
                                                   float* __restrict__ emb) {
  int b = blockIdx.x, chunk = blockIdx.y;
  int d = threadIdx.x;
  float acc = 0.0f;
  if (d < DD) {
    const float* base = node_out + ((size_t)(b * NN + chunk * 256)) * 144 + d;
    for (int n = 0; n < 256; ++n) acc += base[(size_t)n * 144];
    acc = acc * W_out[d] * (1.0f / 2048.0f);
  }
  __shared__ float red[256];
  red[threadIdx.x] = acc;
  __syncthreads();
  for (int off = 128; off >= 1; off >>= 1) {
    if (threadIdx.x < off) red[threadIdx.x] += red[threadIdx.x + off];
    __syncthreads();
  }
  if (threadIdx.x == 0) {
    float v = red[0];
    if (chunk == 0) v += b_out[0];
    atomicAdd(&emb[b], v);
  }
}

// ---------------------------------------------------------------------------
// Finalize: copy f32 emb -> f32 d_out (idempotent across graph replays).
// ---------------------------------------------------------------------------
__global__ void finalize_kernel(const float* __restrict__ emb, float* __restrict__ outp) {
  int t = threadIdx.x;
  if (t < NB) outp[t] = emb[t];
}

// ---------------------------------------------------------------------------
extern "C" void kernel_launch(void* const* d_in, const int* in_sizes, int n_in,
                              void* d_out, int out_size, void* d_ws, size_t ws_size,
                              hipStream_t stream) {
  const float* feats = (const float*)d_in[0];
  const float* coors = (const float*)d_in[1];
  const float* W_e1 = (const float*)d_in[3];
  const float* b_e1 = (const float*)d_in[4];
  const float* W_e2 = (const float*)d_in[5];
  const float* b_e2 = (const float*)d_in[6];
  const float* ln_g = (const float*)d_in[11];
  const float* ln_b = (const float*)d_in[12];
  const float* W_n1 = (const float*)d_in[13];
  const float* b_n1 = (const float*)d_in[14];
  const float* W_n2 = (const float*)d_in[15];
  const float* b_n2 = (const float*)d_in[16];
  const float* W_out = (const float*)d_in[17];
  const float* b_out = (const float*)d_in[18];
  float* out = (float*)d_out;

  char* ws = (char*)d_ws;
  const size_t OFF_IDX = 0;
  const size_t OFF_DIST = 1310720;
  const size_t OFF_MI = 2621440;
  const size_t OFF_AP = 4718592;
  const size_t OFF_BM = 88604672;
  const size_t OFF_NIN = OFF_AP;              // reuse after edge kernel
  const size_t OFF_HN = OFF_AP + 20971520;
  const size_t OFF_NOUT = OFF_HN + 37748736;
  const size_t OFF_EMB = 172490752;

  int* idx = (int*)(ws + OFF_IDX);
  float* dist = (float*)(ws + OFF_DIST);
  float* m_i = (float*)(ws + OFF_MI);
  float* Ap = (float*)(ws + OFF_AP);
  float* Bm = (float*)(ws + OFF_BM);
  float* node_in = (float*)(ws + OFF_NIN);
  float* hnode = (float*)(ws + OFF_HN);
  float* node_out = (float*)(ws + OFF_NOUT);
  float* emb = (float*)(ws + OFF_EMB);

  hipMemsetAsync(m_i, 0, (size_t)NNODES * 16 * 4, stream);
  hipMemsetAsync(emb, 0, (size_t)NB * 4, stream);

  brute_knn<<<dim3(NNODES), dim3(256), 0, stream>>>(coors, idx, dist);

  // A' = feats @ W_e1[0:142] + b_e1 ; Bm = feats @ W_e1[142:284]
  brute_lin<<<dim3(NNODES / 8), dim3(256), 0, stream>>>(
      feats, DD, DD, W_e1, E1OUT, 0, E1OUT, b_e1, nullptr, 0, Ap, APITCH, 0);
  brute_lin<<<dim3(NNODES / 8), dim3(256), 0, stream>>>(
      feats, DD, DD, W_e1, E1OUT, 142, E1OUT, nullptr, nullptr, 0, Bm, APITCH, 0);

  edge_f32_kernel<<<dim3(NEDGES / 8), dim3(512), 0, stream>>>(
      Ap, Bm, idx, dist, W_e1, W_e2, b_e2, m_i);

  node_prep<<<dim3(NNODES / 4), dim3(256), 0, stream>>>(feats, m_i, ln_g, ln_b, node_in);

  // h = silu(node_in @ W_n1 + b_n1)
  brute_lin<<<dim3(NNODES / 8), dim3(256), 0, stream>>>(
      node_in, 160, 158, W_n1, 284, 0, 284, b_n1, nullptr, 0, hnode, 288, 1);
  // node_out = h @ W_n2 + b_n2 + feats
  brute_lin<<<dim3(NNODES / 8), dim3(256), 0, stream>>>(
      hnode, 288, 284, W_n2, DD, 0, DD, b_n2, feats, DD, node_out, 144, 0);

  pool_kernel<<<dim3(NB, 8), dim3(256), 0, stream>>>(node_out, W_out, b_out, emb);

  finalize_kernel<<<dim3(1), dim3(64), 0, stream>>>(emb, out);
}

// Round 6
// 2183.781 us; speedup vs baseline: 5.5283x; 5.5283x over previous
//
#include <hip/hip_runtime.h>

// ---------------------------------------------------------------------------
// EGNN scoring model, MI355X (gfx950).
// R6: reintroduce wave-parallel KNN (provably equivalent to R5's passing
// brute KNN: identical fp ops for d2, lexicographic (dist,idx) min selection
// == serial strict-< argmin). Everything else byte-identical to passing R5.
// Attribution discipline: ONE structural variable per round.
// ---------------------------------------------------------------------------

typedef unsigned int u32;
typedef unsigned long long u64;

#define NB 16
#define NN 2048
#define DD 142
#define KNNK 10
#define NNODES (NB * NN)        // 32768
#define NEDGES (NNODES * KNNK)  // 327680
#define E1OUT 610
#define APITCH 640

__device__ __forceinline__ float siluf(float x) { return x / (1.0f + __expf(-x)); }

__device__ __forceinline__ u64 wave_min_u64(u64 v) {
#pragma unroll
  for (int off = 32; off >= 1; off >>= 1) {
    u32 lo = (u32)v, hi = (u32)(v >> 32);
    u32 olo = (u32)__shfl_xor((int)lo, off, 64);
    u32 ohi = (u32)__shfl_xor((int)hi, off, 64);
    u64 o = ((u64)ohi << 32) | (u64)olo;
    v = (o < v) ? o : v;
  }
  return v;
}

// ---------------------------------------------------------------------------
// Wave-parallel KNN: one wave per node; bit-exact fp32 distances
// ((dx2+dy2)+dz2, same op sequence as brute/np); per-lane sorted top-10 of
// packed u64 (dist_bits<<32)|j; wave merge by repeated global min.
// Tie-break = lower index. Emits GLOBAL neighbor index.
// ---------------------------------------------------------------------------
__global__ __launch_bounds__(256) void knn_kernel(const float* __restrict__ coors,
                                                  int* __restrict__ idxo,
                                                  float* __restrict__ disto) {
  __shared__ float cl[NN * 3];
  int b = blockIdx.x >> 9;           // 512 blocks per batch
  int i0 = (blockIdx.x & 511) << 2;  // 4 nodes per block (4 waves)
  for (int t = threadIdx.x; t < NN * 3; t += 256) cl[t] = coors[b * NN * 3 + t];
  __syncthreads();
  int wave = threadIdx.x >> 6, lane = threadIdx.x & 63;
  int il = i0 + wave;
  float xi = cl[il * 3 + 0], yi = cl[il * 3 + 1], zi = cl[il * 3 + 2];
  u64 r[KNNK];
#pragma unroll
  for (int t = 0; t < KNNK; ++t) r[t] = ~0ull;
  for (int j0 = 0; j0 < NN; j0 += 64) {
    int j = j0 + lane;
    float dx = __fadd_rn(xi, -cl[j * 3 + 0]);
    float dy = __fadd_rn(yi, -cl[j * 3 + 1]);
    float dz = __fadd_rn(zi, -cl[j * 3 + 2]);
    float d2 = __fadd_rn(__fadd_rn(__fmul_rn(dx, dx), __fmul_rn(dy, dy)), __fmul_rn(dz, dz));
    u64 cand = ((u64)__float_as_uint(d2) << 32) | (u64)(u32)j;
    if (cand < r[KNNK - 1]) {
      r[KNNK - 1] = cand;
#pragma unroll
      for (int t = KNNK - 1; t > 0; --t) {
        if (r[t] < r[t - 1]) { u64 tmp = r[t - 1]; r[t - 1] = r[t]; r[t] = tmp; }
      }
    }
  }
  int gi = b * NN + il;
#pragma unroll
  for (int t = 0; t < KNNK; ++t) {
    u64 head = r[0];
    u64 m = wave_min_u64(head);
    if (lane == t) {
      idxo[(size_t)gi * KNNK + t] = b * NN + (int)(u32)(m & 0xffffffffu);  // GLOBAL
      disto[(size_t)gi * KNNK + t] = __uint_as_float((u32)(m >> 32));
    }
    if (head == m) {
#pragma unroll
      for (int q = 0; q < KNNK - 1; ++q) r[q] = r[q + 1];
      r[KNNK - 1] = ~0ull;
    }
  }
}

// ---------------------------------------------------------------------------
// Brute linear (unchanged from passing R5): Y = act(X @ W[r0:r0+K] + b)(+res)
// ---------------------------------------------------------------------------
__global__ __launch_bounds__(256) void brute_lin(
    const float* __restrict__ X, int ldx, int K,
    const float* __restrict__ W, int ldw, int r0, int Ncols,
    const float* __restrict__ bias, const float* __restrict__ resid, int ldr,
    float* __restrict__ Y, int ldy, int doSilu) {
  __shared__ float Xs[8 * 284];
  int n0 = blockIdx.x * 8;
  int tid = threadIdx.x;
  for (int p = tid; p < 8 * K; p += 256) {
    int n = p / K, k = p - n * K;
    Xs[n * K + k] = X[(size_t)(n0 + n) * ldx + k];
  }
  __syncthreads();
  float acc[8][3];
#pragma unroll
  for (int n = 0; n < 8; ++n)
#pragma unroll
    for (int s = 0; s < 3; ++s) acc[n][s] = 0.0f;
  int e1 = tid + 256, e2 = tid + 512;
  for (int k = 0; k < K; ++k) {
    const float* wr = W + (size_t)(r0 + k) * ldw;
    float w0 = (tid < Ncols) ? wr[tid] : 0.0f;
    float w1 = (e1 < Ncols) ? wr[e1] : 0.0f;
    float w2 = (e2 < Ncols) ? wr[e2] : 0.0f;
#pragma unroll
    for (int n = 0; n < 8; ++n) {
      float xv = Xs[n * K + k];
      acc[n][0] += xv * w0;
      acc[n][1] += xv * w1;
      acc[n][2] += xv * w2;
    }
  }
#pragma unroll
  for (int n = 0; n < 8; ++n) {
#pragma unroll
    for (int s = 0; s < 3; ++s) {
      int e = tid + s * 256;
      if (e < Ncols) {
        float v = acc[n][s];
        if (bias) v += bias[e];
        if (doSilu) v = siluf(v);
        if (resid) v += resid[(size_t)(n0 + n) * ldr + e];
        Y[(size_t)(n0 + n) * ldy + e] = v;
      }
    }
  }
}

// ---------------------------------------------------------------------------
// Edge kernel, plain fp32 (unchanged from passing R5). One wave per edge.
// ---------------------------------------------------------------------------
struct EdgeF32Lds {
  float WdT[640][22];
  float BE2[16];
  float DF[8][24];
};

__global__ __launch_bounds__(512) void edge_f32_kernel(
    const float* __restrict__ Ap, const float* __restrict__ Bmm,
    const int* __restrict__ idxE, const float* __restrict__ distE,
    const float* __restrict__ W_e1, const float* __restrict__ W_e2,
    const float* __restrict__ b_e2, float* __restrict__ m_i) {
  __shared__ EdgeF32Lds L;
  int tid = threadIdx.x;
  for (int p = tid; p < 21 * 640; p += 512) {
    int t = p / 640, e = p - t * 640;
    L.WdT[e][t] = (e < E1OUT) ? W_e1[(284 + t) * E1OUT + e] : 0.0f;
  }
  if (tid < 16) L.BE2[tid] = b_e2[tid];

  int wave = tid >> 6, lane = tid & 63;
  int E = blockIdx.x * 8 + wave;
  int i = E / 10;
  int j = idxE[E];
  float d2 = distE[E];
  if (lane < 21) {
    float v;
    if (lane < 10) v = sinf(d2 / (float)(1 << lane));
    else if (lane < 20) v = cosf(d2 / (float)(1 << (lane - 10)));
    else v = d2;
    L.DF[wave][lane] = v;
  }
  __syncthreads();

  float df[21];
#pragma unroll
  for (int t = 0; t < 21; ++t) df[t] = L.DF[wave][t];

  const float* aprow = Ap + (size_t)i * APITCH;
  const float* bmrow = Bmm + (size_t)j * APITCH;
  float z[16];
#pragma unroll
  for (int c = 0; c < 16; ++c) z[c] = 0.0f;

  for (int e = lane; e < E1OUT; e += 64) {
    float h = aprow[e] + bmrow[e];
#pragma unroll
    for (int t = 0; t < 21; ++t) h += df[t] * L.WdT[e][t];
    float hs = siluf(h);
    const float4* w2r = (const float4*)(W_e2 + e * 16);
    float4 w0 = w2r[0], w1 = w2r[1], w2 = w2r[2], w3 = w2r[3];
    z[0] += hs * w0.x;  z[1] += hs * w0.y;  z[2] += hs * w0.z;  z[3] += hs * w0.w;
    z[4] += hs * w1.x;  z[5] += hs * w1.y;  z[6] += hs * w1.z;  z[7] += hs * w1.w;
    z[8] += hs * w2.x;  z[9] += hs * w2.y;  z[10] += hs * w2.z; z[11] += hs * w2.w;
    z[12] += hs * w3.x; z[13] += hs * w3.y; z[14] += hs * w3.z; z[15] += hs * w3.w;
  }

  float zsel = 0.0f;
#pragma unroll
  for (int c = 0; c < 16; ++c) {
    float v = z[c];
#pragma unroll
    for (int off = 32; off >= 1; off >>= 1) v += __shfl_xor(v, off, 64);
    if (lane == c) zsel = v;
  }
  if (lane < 16) {
    float m = siluf(zsel + L.BE2[lane]);
    atomicAdd(&m_i[(size_t)i * 16 + lane], m);
  }
}

// ---------------------------------------------------------------------------
// LayerNorm + concat m_i -> node_in[32768][160]  (unchanged)
// ---------------------------------------------------------------------------
__global__ __launch_bounds__(256) void node_prep(const float* __restrict__ feats,
                                                 const float* __restrict__ m_i,
                                                 const float* __restrict__ ln_g,
                                                 const float* __restrict__ ln_b,
                                                 float* __restrict__ node_in) {
  int wave = threadIdx.x >> 6, lane = threadIdx.x & 63;
  int i = blockIdx.x * 4 + wave;
  const float* fr = feats + (size_t)i * DD;
  float x0 = fr[lane];
  float x1 = fr[lane + 64];
  float x2 = (lane < 14) ? fr[lane + 128] : 0.0f;
  float s = x0 + x1 + x2;
#pragma unroll
  for (int off = 32; off >= 1; off >>= 1) s += __shfl_xor(s, off, 64);
  float mu = s / 142.0f;
  float d0 = x0 - mu, d1 = x1 - mu, d2 = (lane < 14) ? (x2 - mu) : 0.0f;
  float ss = d0 * d0 + d1 * d1 + d2 * d2;
#pragma unroll
  for (int off = 32; off >= 1; off >>= 1) ss += __shfl_xor(ss, off, 64);
  float var = ss / 142.0f;
  float rstd = 1.0f / sqrtf(var + 1e-5f);
  float* o = node_in + (size_t)i * 160;
  o[lane] = d0 * rstd * ln_g[lane] + ln_b[lane];
  o[lane + 64] = d1 * rstd * ln_g[lane + 64] + ln_b[lane + 64];
  if (lane < 14) o[lane + 128] = d2 * rstd * ln_g[lane + 128] + ln_b[lane + 128];
  if (lane < 16) o[142 + lane] = m_i[i * 16 + lane];
}

// ---------------------------------------------------------------------------
// Masked mean pool fused with head -> f32 emb accumulator (unchanged)
// ---------------------------------------------------------------------------
__global__ __launch_bounds__(256) void pool_kernel(const float* __restrict__ node_out,
                                                   const float* __restrict__ W_out,
                                                   const float* __restrict__ b_out,
                                                   float* __restrict__ emb) {
  int b = blockIdx.x, chunk = blockIdx.y;
  int d = threadIdx.x;
  float acc = 0.0f;
  if (d < DD) {
    const float* base = node_out + ((size_t)(b * NN + chunk * 256)) * 144 + d;
    for (int n = 0; n < 256; ++n) acc += base[(size_t)n * 144];
    acc = acc * W_out[d] * (1.0f / 2048.0f);
  }
  __shared__ float red[256];
  red[threadIdx.x] = acc;
  __syncthreads();
  for (int off = 128; off >= 1; off >>= 1) {
    if (threadIdx.x < off) red[threadIdx.x] += red[threadIdx.x + off];
    __syncthreads();
  }
  if (threadIdx.x == 0) {
    float v = red[0];
    if (chunk == 0) v += b_out[0];
    atomicAdd(&emb[b], v);
  }
}

__global__ void finalize_kernel(const float* __restrict__ emb, float* __restrict__ outp) {
  int t = threadIdx.x;
  if (t < NB) outp[t] = emb[t];
}

// ---------------------------------------------------------------------------
extern "C" void kernel_launch(void* const* d_in, const int* in_sizes, int n_in,
                              void* d_out, int out_size, void* d_ws, size_t ws_size,
                              hipStream_t stream) {
  const float* feats = (const float*)d_in[0];
  const float* coors = (const float*)d_in[1];
  const float* W_e1 = (const float*)d_in[3];
  const float* b_e1 = (const float*)d_in[4];
  const float* W_e2 = (const float*)d_in[5];
  const float* b_e2 = (const float*)d_in[6];
  const float* ln_g = (const float*)d_in[11];
  const float* ln_b = (const float*)d_in[12];
  const float* W_n1 = (const float*)d_in[13];
  const float* b_n1 = (const float*)d_in[14];
  const float* W_n2 = (const float*)d_in[15];
  const float* b_n2 = (const float*)d_in[16];
  const float* W_out = (const float*)d_in[17];
  const float* b_out = (const float*)d_in[18];
  float* out = (float*)d_out;

  char* ws = (char*)d_ws;
  const size_t OFF_IDX = 0;
  const size_t OFF_DIST = 1310720;
  const size_t OFF_MI = 2621440;
  const size_t OFF_AP = 4718592;
  const size_t OFF_BM = 88604672;
  const size_t OFF_NIN = OFF_AP;              // reuse after edge kernel
  const size_t OFF_HN = OFF_AP + 20971520;
  const size_t OFF_NOUT = OFF_HN + 37748736;
  const size_t OFF_EMB = 172490752;

  int* idx = (int*)(ws + OFF_IDX);
  float* dist = (float*)(ws + OFF_DIST);
  float* m_i = (float*)(ws + OFF_MI);
  float* Ap = (float*)(ws + OFF_AP);
  float* Bm = (float*)(ws + OFF_BM);
  float* node_in = (float*)(ws + OFF_NIN);
  float* hnode = (float*)(ws + OFF_HN);
  float* node_out = (float*)(ws + OFF_NOUT);
  float* emb = (float*)(ws + OFF_EMB);

  hipMemsetAsync(m_i, 0, (size_t)NNODES * 16 * 4, stream);
  hipMemsetAsync(emb, 0, (size_t)NB * 4, stream);

  knn_kernel<<<dim3(NB * 512), dim3(256), 0, stream>>>(coors, idx, dist);

  brute_lin<<<dim3(NNODES / 8), dim3(256), 0, stream>>>(
      feats, DD, DD, W_e1, E1OUT, 0, E1OUT, b_e1, nullptr, 0, Ap, APITCH, 0);
  brute_lin<<<dim3(NNODES / 8), dim3(256), 0, stream>>>(
      feats, DD, DD, W_e1, E1OUT, 142, E1OUT, nullptr, nullptr, 0, Bm, APITCH, 0);

  edge_f32_kernel<<<dim3(NEDGES / 8), dim3(512), 0, stream>>>(
      Ap, Bm, idx, dist, W_e1, W_e2, b_e2, m_i);

  node_prep<<<dim3(NNODES / 4), dim3(256), 0, stream>>>(feats, m_i, ln_g, ln_b, node_in);

  brute_lin<<<dim3(NNODES / 8), dim3(256), 0, stream>>>(
      node_in, 160, 158, W_n1, 284, 0, 284, b_n1, nullptr, 0, hnode, 288, 1);
  brute_lin<<<dim3(NNODES / 8), dim3(256), 0, stream>>>(
      hnode, 288, 284, W_n2, DD, 0, DD, b_n2, feats, DD, node_out, 144, 0);

  pool_kernel<<<dim3(NB, 8), dim3(256), 0, stream>>>(node_out, W_out, b_out, emb);

  finalize_kernel<<<dim3(1), dim3(64), 0, stream>>>(emb, out);
}